// Round 1
// 1023.656 us; speedup vs baseline: 1.2965x; 1.2965x over previous
//
#include <hip/hip_runtime.h>
#include <math.h>

// FrontierLayerVN: gather -> GVPerceptronVN -> GVLinear(scalar out)
// fp32 3-kernel pipeline. ws layout (floats): vnorm M*64 | ovec M*96 | osca M*128

#define NSV 0.2f
#define NSS 0.01f

// ---------------- K1: vh / vnorm / out_vec ----------------
// 32 rows per block, 256 threads.
__global__ __launch_bounds__(256) void k1_kernel(
    const float* __restrict__ hvec,   // N x 64 x 3
    const int*   __restrict__ idx,    // M
    const float* __restrict__ Wv1,    // 64 x 64  [c][h]
    const float* __restrict__ Wv2,    // 64 x 32  [h][o]
    float* __restrict__ vnorm_ws,     // M x 64
    float* __restrict__ ovec_ws,      // M x 96
    int M)
{
    __shared__ __align__(16) float sWv1[64*64];
    __shared__ __align__(16) float sWv2[64*32];
    __shared__ __align__(16) float sv[32*196];   // vec rows (stride 196 breaks bank alias); reused for vh
    __shared__ int sidx[32];

    const int tid  = threadIdx.x;
    const int row0 = blockIdx.x * 32;

    // float4 weight staging (4096 + 2048 floats)
    #pragma unroll
    for (int p = 0; p < 4; ++p) {
        int lin = p*256 + tid;
        *(float4*)&sWv1[lin*4] = *(const float4*)&Wv1[lin*4];
    }
    #pragma unroll
    for (int p = 0; p < 2; ++p) {
        int lin = p*256 + tid;
        *(float4*)&sWv2[lin*4] = *(const float4*)&Wv2[lin*4];
    }
    if (tid < 32) {
        int m = row0 + tid;
        sidx[tid] = idx[m < M ? m : M-1];
    }
    __syncthreads();

    // gather 32 vec rows (192 floats = 48 float4 each), coalesced float4
    #pragma unroll
    for (int p = 0; p < 6; ++p) {
        int lin = p*256 + tid;           // float4 index, 1536 total
        int r = lin / 48, e4 = lin % 48;
        *(float4*)&sv[r*196 + e4*4] = *(const float4*)&hvec[(size_t)sidx[r]*192 + e4*4];
    }
    __syncthreads();

    // vh GEMM: thread = (ty: 2 rows, tx: 4 h) x 3 comps
    const int tx = tid & 15;
    const int ty = tid >> 4;
    float acc[2][4][3];
    #pragma unroll
    for (int a = 0; a < 2; ++a)
        #pragma unroll
        for (int b = 0; b < 4; ++b)
            #pragma unroll
            for (int c = 0; c < 3; ++c) acc[a][b][c] = 0.f;

    for (int c = 0; c < 64; ++c) {
        float av[2][3];
        #pragma unroll
        for (int rr = 0; rr < 2; ++rr) {
            int base = (ty*2 + rr)*196 + c*3;
            av[rr][0] = sv[base+0]; av[rr][1] = sv[base+1]; av[rr][2] = sv[base+2];
        }
        float4 w4 = *(const float4*)&sWv1[c*64 + tx*4];
        float wv[4] = {w4.x, w4.y, w4.z, w4.w};
        #pragma unroll
        for (int rr = 0; rr < 2; ++rr)
            #pragma unroll
            for (int hh = 0; hh < 4; ++hh)
                #pragma unroll
                for (int x = 0; x < 3; ++x)
                    acc[rr][hh][x] += av[rr][x] * wv[hh];
    }

    // vnorm = ||vh|| -> ws (float4 per row-chunk)
    #pragma unroll
    for (int rr = 0; rr < 2; ++rr) {
        int m = row0 + ty*2 + rr;
        float4 vn;
        vn.x = sqrtf(acc[rr][0][0]*acc[rr][0][0] + acc[rr][0][1]*acc[rr][0][1] + acc[rr][0][2]*acc[rr][0][2]);
        vn.y = sqrtf(acc[rr][1][0]*acc[rr][1][0] + acc[rr][1][1]*acc[rr][1][1] + acc[rr][1][2]*acc[rr][1][2]);
        vn.z = sqrtf(acc[rr][2][0]*acc[rr][2][0] + acc[rr][2][1]*acc[rr][2][1] + acc[rr][2][2]*acc[rr][2][2]);
        vn.w = sqrtf(acc[rr][3][0]*acc[rr][3][0] + acc[rr][3][1]*acc[rr][3][1] + acc[rr][3][2]*acc[rr][3][2]);
        if (m < M) *(float4*)&vnorm_ws[(size_t)m*64 + tx*4] = vn;
    }

    __syncthreads();   // all reads of sv (vec) done
    // write vh into sv: layout [r][h*3+x]
    #pragma unroll
    for (int rr = 0; rr < 2; ++rr)
        #pragma unroll
        for (int hh = 0; hh < 4; ++hh)
            #pragma unroll
            for (int x = 0; x < 3; ++x)
                sv[(ty*2 + rr)*196 + (tx*4 + hh)*3 + x] = acc[rr][hh][x];
    __syncthreads();

    // out_vec GEMM: thread = (r2: 1 row, to: 4 o) x 3 comps
    const int to = tid & 7;
    const int r2 = tid >> 3;
    float oa[4][3];
    #pragma unroll
    for (int a = 0; a < 4; ++a)
        #pragma unroll
        for (int c = 0; c < 3; ++c) oa[a][c] = 0.f;

    for (int h = 0; h < 64; ++h) {
        int base = r2*196 + h*3;
        float a0 = sv[base+0], a1 = sv[base+1], a2 = sv[base+2];
        float4 w4 = *(const float4*)&sWv2[h*32 + to*4];
        float wv[4] = {w4.x, w4.y, w4.z, w4.w};
        #pragma unroll
        for (int oo = 0; oo < 4; ++oo) {
            oa[oo][0] += a0*wv[oo];
            oa[oo][1] += a1*wv[oo];
            oa[oo][2] += a2*wv[oo];
        }
    }
    int m2 = row0 + r2;
    if (m2 < M) {
        float t[12];
        #pragma unroll
        for (int oo = 0; oo < 4; ++oo)
            #pragma unroll
            for (int x = 0; x < 3; ++x) t[oo*3+x] = oa[oo][x];
        float4* dst = (float4*)&ovec_ws[(size_t)m2*96 + to*12];
        dst[0] = make_float4(t[0], t[1], t[2],  t[3]);
        dst[1] = make_float4(t[4], t[5], t[6],  t[7]);
        dst[2] = make_float4(t[8], t[9], t[10], t[11]);
    }
}

// ---------------- K2: osca = [vnorm | sca_gather] @ Ws_1 ----------------
// 128 rows x 128 cols per block, KT=32, 8x8 acc per thread.
// Software pipeline: global loads for tile kt+2 issued while tile kt computes
// (register staging, single LDS buffer) so the random hsca gather latency
// hides under the ~2k-FMA compute phase.
__global__ __launch_bounds__(256) void k2_kernel(
    const float* __restrict__ hsca,     // N x 256
    const int*   __restrict__ idx,
    const float* __restrict__ Ws1,      // 320 x 128
    const float* __restrict__ vnorm_ws, // M x 64
    float* __restrict__ osca_ws,        // M x 128
    int M)
{
    __shared__ __align__(16) float sX[128*33];
    __shared__ __align__(16) float sW[32*128];
    __shared__ int sidx[128];

    const int tid  = threadIdx.x;
    const int row0 = blockIdx.x * 128;
    const int tx = tid & 15;
    const int ty = tid >> 4;

    if (tid < 128) {
        int m = row0 + tid;
        sidx[tid] = idx[m < M ? m : M-1];
    }
    __syncthreads();   // sidx readable

    // per-thread staging descriptors (4 float4 of X, 4 float4 of W per tile)
    const float* xptr[4];   // hsca gather base (kt >= 2)
    const float* vptr[4];   // vnorm base (kt < 2)
    #pragma unroll
    for (int p = 0; p < 4; ++p) {
        int lin = p*256 + tid;       // float4 index into 128x32 tile
        int r = lin >> 3, c4 = lin & 7;
        int m = row0 + r; if (m >= M) m = M - 1;
        xptr[p] = hsca + (size_t)sidx[r]*256 + c4*4;
        vptr[p] = vnorm_ws + (size_t)m*64 + c4*4;
    }
    const float* wsrc = Ws1 + (size_t)tid*4;

    float4 xr[4], wr[4];

    auto load_tile = [&](int kt) {
        if (kt < 2) {
            #pragma unroll
            for (int p = 0; p < 4; ++p) xr[p] = *(const float4*)(vptr[p] + kt*32);
        } else {
            #pragma unroll
            for (int p = 0; p < 4; ++p) xr[p] = *(const float4*)(xptr[p] + (kt-2)*32);
        }
        const float* w = wsrc + (size_t)kt*4096;
        #pragma unroll
        for (int p = 0; p < 4; ++p) wr[p] = *(const float4*)(w + p*1024);
    };
    auto store_tile = [&]() {
        #pragma unroll
        for (int p = 0; p < 4; ++p) {
            int lin = p*256 + tid;
            int r = lin >> 3, c4 = lin & 7;
            float* d = &sX[r*33 + c4*4];
            d[0] = xr[p].x; d[1] = xr[p].y; d[2] = xr[p].z; d[3] = xr[p].w;
            *(float4*)&sW[lin*4] = wr[p];
        }
    };

    float acc[8][8];
    #pragma unroll
    for (int i = 0; i < 8; ++i)
        #pragma unroll
        for (int j = 0; j < 8; ++j) acc[i][j] = 0.f;

    // prologue: tile0 -> LDS, tile1 in flight
    load_tile(0);
    store_tile();
    load_tile(1);
    __syncthreads();

    #pragma unroll 1
    for (int kt = 0; kt < 10; ++kt) {
        #pragma unroll 8
        for (int k = 0; k < 32; ++k) {
            float a[8];
            #pragma unroll
            for (int rr = 0; rr < 8; ++rr) a[rr] = sX[(ty*8 + rr)*33 + k];
            float4 b0 = *(const float4*)&sW[k*128 + tx*4];
            float4 b1 = *(const float4*)&sW[k*128 + 64 + tx*4];
            float b[8] = {b0.x, b0.y, b0.z, b0.w, b1.x, b1.y, b1.z, b1.w};
            #pragma unroll
            for (int rr = 0; rr < 8; ++rr)
                #pragma unroll
                for (int cc = 0; cc < 8; ++cc)
                    acc[rr][cc] += a[rr] * b[cc];
        }
        if (kt < 9) {
            __syncthreads();           // all reads of current tile done
            store_tile();              // tile kt+1 regs -> LDS (loads landed during compute)
            if (kt < 8) load_tile(kt + 2);   // issue next-next tile
            __syncthreads();           // tile kt+1 visible
        }
    }

    // thread covers cols {tx*4..tx*4+3} and {64+tx*4..64+tx*4+3}
    #pragma unroll
    for (int rr = 0; rr < 8; ++rr) {
        int m = row0 + ty*8 + rr;
        if (m < M) {
            float4 s0 = make_float4(acc[rr][0], acc[rr][1], acc[rr][2], acc[rr][3]);
            float4 s1 = make_float4(acc[rr][4], acc[rr][5], acc[rr][6], acc[rr][7]);
            *(float4*)&osca_ws[(size_t)m*128 + tx*4]      = s0;
            *(float4*)&osca_ws[(size_t)m*128 + 64 + tx*4] = s1;
        }
    }
}

// ---------------- K3: gate, VNLeakyReLU, layer2 scalar ----------------
// 32 rows per block, 256 threads = 8 o-groups x 32 rows.
__global__ __launch_bounds__(256) void k3_kernel(
    const float* __restrict__ osca,   // M x 128 (raw, pre-leaky)
    const float* __restrict__ ovec,   // M x 96 (raw, pre-gate)
    const float* __restrict__ Wg,     // 128 x 32
    const float* __restrict__ bg,     // 32
    const float* __restrict__ Wd,     // 32 x 32 [c][o]
    const float* __restrict__ Wv12,   // 32 x 32 [c][h]
    const float* __restrict__ Ws2,    // 160 x 1
    float* __restrict__ out,          // M
    int M)
{
    __shared__ __align__(16) float sS[32*132];   // osca rows, padded
    __shared__ __align__(16) float sV[32*100];   // vec rows (gated -> v2), padded
    __shared__ __align__(16) float sWg[128*32];
    __shared__ __align__(16) float sWd[32*32];
    __shared__ __align__(16) float sW12[32*32];
    __shared__ float sWs2[160];
    __shared__ float sbg[32];

    const int tid  = threadIdx.x;
    const int row0 = blockIdx.x * 32;

    #pragma unroll
    for (int p = 0; p < 16; ++p) sWg[p*256 + tid] = Wg[p*256 + tid];
    #pragma unroll
    for (int p = 0; p < 4; ++p) {
        sWd[p*256 + tid]  = Wd[p*256 + tid];
        sW12[p*256 + tid] = Wv12[p*256 + tid];
    }
    if (tid < 160) sWs2[tid] = Ws2[tid];
    if (tid < 32)  sbg[tid]  = bg[tid];

    #pragma unroll
    for (int p = 0; p < 16; ++p) {
        int lin = p*256 + tid;
        int r = lin >> 7, j = lin & 127;
        int m = row0 + r; if (m >= M) m = M - 1;
        sS[r*132 + j] = osca[(size_t)m*128 + j];
    }
    #pragma unroll
    for (int p = 0; p < 12; ++p) {
        int lin = p*256 + tid;
        int r = lin / 96, e = lin % 96;
        int m = row0 + r; if (m >= M) m = M - 1;
        sV[r*100 + e] = ovec[(size_t)m*96 + e];
    }
    __syncthreads();

    const int to = tid & 7;    // 4 o's each
    const int r  = tid >> 3;   // 1 row

    // gate GEMM
    float g[4] = {0.f, 0.f, 0.f, 0.f};
    for (int j = 0; j < 128; ++j) {
        float a = sS[r*132 + j];
        float4 w4 = *(const float4*)&sWg[j*32 + to*4];
        g[0] += a*w4.x; g[1] += a*w4.y; g[2] += a*w4.z; g[3] += a*w4.w;
    }
    float v1[4][3];
    #pragma unroll
    for (int oo = 0; oo < 4; ++oo) {
        int o = to*4 + oo;
        float gt = 1.f / (1.f + __expf(-(g[oo] + sbg[o])));
        #pragma unroll
        for (int x = 0; x < 3; ++x) v1[oo][x] = gt * sV[r*100 + o*3 + x];
    }
    // overwrite own slots with gated vec (each slot owned by exactly one thread)
    #pragma unroll
    for (int oo = 0; oo < 4; ++oo)
        #pragma unroll
        for (int x = 0; x < 3; ++x)
            sV[r*100 + (to*4 + oo)*3 + x] = v1[oo][x];
    __syncthreads();

    // d GEMM
    float dd[4][3];
    #pragma unroll
    for (int a = 0; a < 4; ++a)
        #pragma unroll
        for (int c = 0; c < 3; ++c) dd[a][c] = 0.f;
    for (int c = 0; c < 32; ++c) {
        int base = r*100 + c*3;
        float a0 = sV[base+0], a1 = sV[base+1], a2 = sV[base+2];
        float4 w4 = *(const float4*)&sWd[c*32 + to*4];
        float wv[4] = {w4.x, w4.y, w4.z, w4.w};
        #pragma unroll
        for (int oo = 0; oo < 4; ++oo) {
            dd[oo][0] += a0*wv[oo];
            dd[oo][1] += a1*wv[oo];
            dd[oo][2] += a2*wv[oo];
        }
    }
    // VN leaky relu
    float v2[4][3];
    #pragma unroll
    for (int oo = 0; oo < 4; ++oo) {
        float dot = v1[oo][0]*dd[oo][0] + v1[oo][1]*dd[oo][1] + v1[oo][2]*dd[oo][2];
        float dsq = dd[oo][0]*dd[oo][0] + dd[oo][1]*dd[oo][1] + dd[oo][2]*dd[oo][2];
        float coef = dot / (dsq + 1e-6f);
        #pragma unroll
        for (int x = 0; x < 3; ++x) {
            float pj = v1[oo][x] - coef*dd[oo][x];
            v2[oo][x] = NSV*v1[oo][x] + (1.f - NSV)*((dot >= 0.f) ? v1[oo][x] : pj);
        }
    }
    __syncthreads();   // all phase-C reads of sV done
    #pragma unroll
    for (int oo = 0; oo < 4; ++oo)
        #pragma unroll
        for (int x = 0; x < 3; ++x)
            sV[r*100 + (to*4 + oo)*3 + x] = v2[oo][x];
    __syncthreads();

    // layer-2 vh2 GEMM (h = to*4+hh)
    float h2[4][3];
    #pragma unroll
    for (int a = 0; a < 4; ++a)
        #pragma unroll
        for (int c = 0; c < 3; ++c) h2[a][c] = 0.f;
    for (int c = 0; c < 32; ++c) {
        int base = r*100 + c*3;
        float a0 = sV[base+0], a1 = sV[base+1], a2 = sV[base+2];
        float4 w4 = *(const float4*)&sW12[c*32 + to*4];
        float wv[4] = {w4.x, w4.y, w4.z, w4.w};
        #pragma unroll
        for (int hh = 0; hh < 4; ++hh) {
            h2[hh][0] += a0*wv[hh];
            h2[hh][1] += a1*wv[hh];
            h2[hh][2] += a2*wv[hh];
        }
    }
    // final dot: vnorm2 part + leaky(sca) part
    float partial = 0.f;
    #pragma unroll
    for (int hh = 0; hh < 4; ++hh) {
        float vn = sqrtf(h2[hh][0]*h2[hh][0] + h2[hh][1]*h2[hh][1] + h2[hh][2]*h2[hh][2]);
        partial += vn * sWs2[to*4 + hh];
    }
    #pragma unroll
    for (int t = 0; t < 16; ++t) {
        int j = to*16 + t;
        float s = sS[r*132 + j];
        s = (s >= 0.f) ? s : NSS*s;
        partial += s * sWs2[32 + j];
    }
    partial += __shfl_xor(partial, 1);
    partial += __shfl_xor(partial, 2);
    partial += __shfl_xor(partial, 4);
    if (to == 0 && row0 + r < M) out[row0 + r] = partial;
}

extern "C" void kernel_launch(void* const* d_in, const int* in_sizes, int n_in,
                              void* d_out, int out_size, void* d_ws, size_t ws_size,
                              hipStream_t stream) {
    const float* hsca  = (const float*)d_in[0];
    const float* hvec  = (const float*)d_in[1];
    const int*   idx   = (const int*)d_in[2];
    const float* Wv1_1 = (const float*)d_in[3];
    const float* Wv2_1 = (const float*)d_in[4];
    const float* Ws_1  = (const float*)d_in[5];
    const float* Wg_1  = (const float*)d_in[6];
    const float* bg_1  = (const float*)d_in[7];
    const float* Wd_1  = (const float*)d_in[8];
    const float* Wv1_2 = (const float*)d_in[9];
    // d_in[10] = Wv2_2 (unused: vec branch of layer 2 is dropped)
    const float* Ws_2  = (const float*)d_in[11];
    // d_in[12] = Wg_2, d_in[13] = bg_2 (unused)

    const int M = in_sizes[2];
    float* out = (float*)d_out;

    float* ws       = (float*)d_ws;
    float* vnorm_ws = ws;                      // M*64
    float* ovec_ws  = ws + (size_t)M*64;       // M*96
    float* osca_ws  = ws + (size_t)M*160;      // M*128  (total M*288 floats = 230 MB)

    const int nb32  = (M + 31) / 32;
    const int nb128 = (M + 127) / 128;

    k1_kernel<<<nb32, 256, 0, stream>>>(hvec, idx, Wv1_1, Wv2_1, vnorm_ws, ovec_ws, M);
    k2_kernel<<<nb128, 256, 0, stream>>>(hsca, idx, Ws_1, vnorm_ws, osca_ws, M);
    k3_kernel<<<nb32, 256, 0, stream>>>(osca_ws, ovec_ws, Wg_1, bg_1, Wd_1, Wv1_2, Ws_2, out, M);
}